// Round 10
// baseline (259.388 us; speedup 1.0000x reference)
//
#include <hip/hip_runtime.h>

typedef _Float16 f16;
typedef __attribute__((ext_vector_type(2))) _Float16 f16x2;
typedef __attribute__((ext_vector_type(2))) __fp16   hf16x2;  // cvt_pkrtz native return
typedef __attribute__((ext_vector_type(4))) _Float16 f16x4;
typedef __attribute__((ext_vector_type(8))) _Float16 f16x8;
typedef __attribute__((ext_vector_type(4))) float    f32x4;

#define D_MODEL 1024
#define HEADS   16
#define DH      64
#define SEQ     2048
#define BATCH   4
#define SSCALE  0.1803368801111204f   // 1/sqrt(64) * log2(e)

// async 16B global->LDS; lds dst is wave-uniform base + lane*16
__device__ __forceinline__ void gload_lds16(const void* g, void* lds) {
  __builtin_amdgcn_global_load_lds(
      (const __attribute__((address_space(1))) unsigned int*)g,
      (__attribute__((address_space(3))) unsigned int*)lds, 16, 0, 0);
}

// ---------------- prep: cast x, transpose W (merged: one dispatch; r0 form) ----------------
__global__ __launch_bounds__(256) void prep_kernel(const float* __restrict__ x,
                                                   const float* __restrict__ Wq,
                                                   const float* __restrict__ Wk,
                                                   const float* __restrict__ Wv,
                                                   f16* __restrict__ xb,
                                                   f16* __restrict__ wt) {
  if (blockIdx.x < 8192) {                     // cast x fp32 -> f16
    int i = blockIdx.x * 256 + threadIdx.x;
    float4 v = ((const float4*)x)[i];
    f16x4 h;
    h[0] = (f16)v.x; h[1] = (f16)v.y; h[2] = (f16)v.z; h[3] = (f16)v.w;
    ((f16x4*)xb)[i] = h;
    return;
  }
  int bid = blockIdx.x - 8192;                 // W [K][N] fp32 -> Wt [N][K] f16
  int z = bid >> 8, rem = bid & 255;
  const float* W = z == 0 ? Wq : (z == 1 ? Wk : Wv);
  f16* out = wt + (size_t)z * D_MODEL * D_MODEL;
  __shared__ float tile[64][65];
  int n0 = (rem & 15) * 64, k0 = (rem >> 4) * 64;
  int tx = threadIdx.x & 63, ty = threadIdx.x >> 6;
#pragma unroll
  for (int r = 0; r < 16; ++r)
    tile[ty * 16 + r][tx] = W[(size_t)(k0 + ty * 16 + r) * D_MODEL + n0 + tx];
  __syncthreads();
#pragma unroll
  for (int r = 0; r < 16; ++r)
    out[(size_t)(n0 + ty * 16 + r) * D_MODEL + k0 + tx] = (f16)tile[tx][ty * 16 + r];
}

// ---------------- QKV projection GEMM (r4 verbatim: 69.5us measured best) ----------------
// 128x128 tile, BK=32, ring-3 LDS + counted vmcnt(4). XCD-locality remap:
// XCD j (= bid%8) owns a contiguous m-band (y' = j*8 + t%8) -> per-XCD L2
// working set = 2MB xb band + 2MB wt(z). Bijective over 1536 blocks.
__global__ __launch_bounds__(256, 3) void qkv_gemm_kernel(
    const f16* __restrict__ xb, const f16* __restrict__ wt_all,
    const float* __restrict__ bq, const float* __restrict__ bk, const float* __restrict__ bv,
    f16* __restrict__ qout, f16* __restrict__ kout, f16* __restrict__ vtout) {
  const int bid = blockIdx.x;
  const int j = bid & 7, t = bid >> 3;
  const int by = j * 8 + (t & 7);            // m-block: contiguous band per XCD
  const int bx = (t >> 3) & 7;               // n-block
  const int z  = t >> 6;                     // q/k/v
  const f16* wt = wt_all + (size_t)z * D_MODEL * D_MODEL;
  const float* bias = z == 0 ? bq : (z == 1 ? bk : bv);
  const int n0 = bx * 128, m0 = by * 128;

  __shared__ f16 As[3][128 * 32];   // 8KB per buffer, ring-3
  __shared__ f16 Bs[3][128 * 32];   // 48KB total -> still 3 blocks/CU

  const int tid = threadIdx.x;
  const int lane = tid & 63, w = tid >> 6;
  const int quad = lane >> 4, l15 = lane & 15;
  const int wm = w & 1, wn = w >> 1;

  const int pce = (quad ^ ((l15 >> 1) & 3)) * 8;
  const int aoff = wm * 2048 + l15 * 32 + pce;
  const int boff = wn * 2048 + l15 * 32 + pce;

  int srow[2], scl[2];
#pragma unroll
  for (int c = 0; c < 2; ++c) {
    int slot = (w * 2 + c) * 64 + lane;
    srow[c] = slot >> 2;
    scl[c] = (slot & 3) ^ ((srow[c] >> 1) & 3);
  }

  f32x4 acc[4][4];
#pragma unroll
  for (int i = 0; i < 4; ++i)
#pragma unroll
    for (int jj = 0; jj < 4; ++jj) acc[i][jj] = (f32x4){0.f, 0.f, 0.f, 0.f};

  // prologue: stage k-tiles 0 and 1 (issue order: tile0's 4 loads, tile1's 4)
#pragma unroll
  for (int tt = 0; tt < 2; ++tt)
#pragma unroll
    for (int c = 0; c < 2; ++c) {
      gload_lds16(xb + (size_t)(m0 + srow[c]) * D_MODEL + tt * 32 + scl[c] * 8, &As[tt][(w * 2 + c) * 512]);
      gload_lds16(wt + (size_t)(n0 + srow[c]) * D_MODEL + tt * 32 + scl[c] * 8, &Bs[tt][(w * 2 + c) * 512]);
    }

  f16x8 aP[4], bP[4];
  int buf = 0;
  for (int it = 0; it < 32; ++it) {
    // retire through this iter's tile; keep next tile's loads airborne
    if (it == 31) { asm volatile("s_waitcnt vmcnt(0)" ::: "memory"); }
    else          { asm volatile("s_waitcnt vmcnt(4)" ::: "memory"); }
    __builtin_amdgcn_s_barrier();
    __builtin_amdgcn_sched_barrier(0);        // pin: nothing crosses the barrier
    if (it < 30) {
      const int sb = buf ? buf - 1 : 2;       // (it+2) % 3
      const int kn = (it + 2) * 32;
#pragma unroll
      for (int c = 0; c < 2; ++c) {
        gload_lds16(xb + (size_t)(m0 + srow[c]) * D_MODEL + kn + scl[c] * 8, &As[sb][(w * 2 + c) * 512]);
        gload_lds16(wt + (size_t)(n0 + srow[c]) * D_MODEL + kn + scl[c] * 8, &Bs[sb][(w * 2 + c) * 512]);
      }
    }
    f16x8 aC[4], bC[4];
#pragma unroll
    for (int mt = 0; mt < 4; ++mt) aC[mt] = *(const f16x8*)(&As[buf][aoff + mt * 512]);
#pragma unroll
    for (int nt = 0; nt < 4; ++nt) bC[nt] = *(const f16x8*)(&Bs[buf][boff + nt * 512]);
    if (it) {
#pragma unroll
      for (int mt = 0; mt < 4; ++mt)
#pragma unroll
        for (int nt = 0; nt < 4; ++nt)
          acc[mt][nt] = __builtin_amdgcn_mfma_f32_16x16x32_f16(aP[mt], bP[nt], acc[mt][nt], 0, 0, 0);
    }
#pragma unroll
    for (int tt = 0; tt < 4; ++tt) { aP[tt] = aC[tt]; bP[tt] = bC[tt]; }
    buf = (buf == 2) ? 0 : buf + 1;
  }
#pragma unroll
  for (int mt = 0; mt < 4; ++mt)
#pragma unroll
    for (int nt = 0; nt < 4; ++nt)
      acc[mt][nt] = __builtin_amdgcn_mfma_f32_16x16x32_f16(aP[mt], bP[nt], acc[mt][nt], 0, 0, 0);

  const float sc = (z == 0) ? SSCALE : 1.0f;
  float bcol[4];
#pragma unroll
  for (int nt = 0; nt < 4; ++nt) bcol[nt] = bias[n0 + wn * 64 + nt * 16 + l15];

  if (z < 2) {
    f16* out = (z == 0) ? qout : kout;
#pragma unroll
    for (int mt = 0; mt < 4; ++mt) {
      int mbase = m0 + wm * 64 + mt * 16 + quad * 4;
#pragma unroll
      for (int nt = 0; nt < 4; ++nt) {
        int n = n0 + wn * 64 + nt * 16 + l15;
        int h = n >> 6, dh = n & 63;
#pragma unroll
        for (int r = 0; r < 4; ++r) {
          int m = mbase + r;
          int b = m >> 11, s = m & 2047;
          out[((size_t)(b * HEADS + h) * SEQ + s) * DH + dh] = (f16)((acc[mt][nt][r] + bcol[nt]) * sc);
        }
      }
    }
  } else {
    // V in PV-fragment order: per (bh,kt) 4096-elem tile, row dh (64 elems),
    // sk' = quad*16 + mt*4 + r, phys 8-elem chunk = (sk'>>3) ^ (dh&7).
#pragma unroll
    for (int mt = 0; mt < 4; ++mt) {
      int mbase = m0 + wm * 64 + mt * 16 + quad * 4;
      int b = mbase >> 11, seq = mbase & 2047;
      int kt = seq >> 6;
#pragma unroll
      for (int nt = 0; nt < 4; ++nt) {
        int n = n0 + wn * 64 + nt * 16 + l15;
        int h = n >> 6, dh = n & 63;
        f16x4 v;
#pragma unroll
        for (int r = 0; r < 4; ++r) v[r] = (f16)(acc[mt][nt][r] + bcol[nt]);
        int phys = (quad * 2 + (mt >> 1)) ^ (dh & 7);
        size_t off = (((size_t)(b * HEADS + h) * 32 + kt) * 4096) + dh * 64 + phys * 8 + (mt & 1) * 4;
        *(f16x4*)(vtout + off) = v;
      }
    }
  }
}

// ---------------- fused flash attention: software-pipelined (QK(kt+1) ∥ exp(kt)) ----------------
// r0 geometry (BQ=256, 4 waves, 2 blocks/CU — best measured) + one-stage loop
// rotation: iteration kt runs exp2/pack(kt) INTERLEAVED with QK(kt+1), then
// PV(kt). exp(kt) needs only st(kt) (regs); QK(kt+1) needs only K(kt+1)
// (staged one iter ahead) — independent, so VALU exp2 issues under the QK
// MFMAs instead of serializing between QK and PV. Ring-3 K/V LDS (48KB, 2
// blocks/CU): slot (kt+2)%3 is re-staged only after the iter-kt barrier, and
// its last reads (K in iter kt-1, V in iter kt-1) precede that barrier.
// Per-mt order = exp-consume(stOld[mt]) then QK-produce(stNew[mt]) so the two
// st arrays' live ranges telescope (~80 regs peak, not 128).
__global__ __launch_bounds__(256, 2) void attn_kernel(
    const f16* __restrict__ q, const f16* __restrict__ k, const f16* __restrict__ vt,
    float* __restrict__ out) {
  const int bh = blockIdx.x;             // (bh, qtile): q-tiles of one head share an XCD
  const int s0 = blockIdx.y * 256;
  const int b = bh >> 4, h = bh & 15;
  const int tid = threadIdx.x, lane = tid & 63, w = tid >> 6;
  const int quad = lane >> 4, l15 = lane & 15;

  __shared__ f16 Ks[3][64 * 64];   // [sk][dh], 8KB per buffer, ring-3
  __shared__ f16 Vs[3][64 * 64];   // PV-fragment order, ring-3 (48KB total)

  const f16* qbase = q + ((size_t)bh * SEQ + s0 + w * 64) * DH;
  const f16* kbase = k + (size_t)bh * SEQ * DH;
  const f16* vbase = vt + (size_t)bh * DH * SEQ;   // tile kt at +kt*4096

  // Q fragments: 4 q-subtiles of 16 per wave
  f16x8 qf[4][2];
#pragma unroll
  for (int qt = 0; qt < 4; ++qt)
#pragma unroll
    for (int ks = 0; ks < 2; ++ks)
      qf[qt][ks] = *(const f16x8*)(qbase + (qt * 16 + l15) * DH + ks * 32 + quad * 8);

  int koff[2];
  koff[0] = l15 * 64 + ((quad ^ (l15 & 7)) * 8);
  koff[1] = l15 * 64 + (((4 + quad) ^ (l15 & 7)) * 8);
  int voff2[2];                    // V b128 reads: half h covers ks=2h,2h+1
  voff2[0] = l15 * 64 + (((quad * 2) ^ (l15 & 7)) * 8);
  voff2[1] = l15 * 64 + (((quad * 2 + 1) ^ (l15 & 7)) * 8);

  int srow[2], scl[2];             // K staging swizzle (V staging is identity)
#pragma unroll
  for (int c = 0; c < 2; ++c) {
    int slot = (w * 2 + c) * 64 + lane;
    srow[c] = slot >> 3;
    scl[c] = (slot & 7) ^ (srow[c] & 7);
  }
  const int vslot = ((w * 2) * 64 + lane) * 8;   // identity V staging offsets
  const int vslot2 = ((w * 2 + 1) * 64 + lane) * 8;

  auto stage = [&](int t, int rs) {
#pragma unroll
    for (int c = 0; c < 2; ++c)
      gload_lds16(kbase + (size_t)(t * 64 + srow[c]) * DH + scl[c] * 8, &Ks[rs][(w * 2 + c) * 512]);
    gload_lds16(vbase + (size_t)t * 4096 + vslot,  &Vs[rs][(w * 2) * 512]);
    gload_lds16(vbase + (size_t)t * 4096 + vslot2, &Vs[rs][(w * 2 + 1) * 512]);
  };

  f32x4 lsum4[4];
#pragma unroll
  for (int qt = 0; qt < 4; ++qt) lsum4[qt] = (f32x4){0.f, 0.f, 0.f, 0.f};
  f32x4 o[4][4];
#pragma unroll
  for (int i = 0; i < 4; ++i)
#pragma unroll
    for (int jj = 0; jj < 4; ++jj) o[i][jj] = (f32x4){0.f, 0.f, 0.f, 0.f};
  const f32x4 Zero = (f32x4){0.f, 0.f, 0.f, 0.f};

  // prologue: stage kt=0 -> ring0, kt=1 -> ring1; then QK(0) -> stA
  stage(0, 0);
  stage(1, 1);
  __syncthreads();

  f32x4 stA[4][4], stB[4][4];
#pragma unroll
  for (int mt = 0; mt < 4; ++mt) {
    f16x8 af0 = *(const f16x8*)(&Ks[0][koff[0] + mt * 1024]);
    f16x8 af1 = *(const f16x8*)(&Ks[0][koff[1] + mt * 1024]);
#pragma unroll
    for (int qt = 0; qt < 4; ++qt) {
      stA[mt][qt] = __builtin_amdgcn_mfma_f32_16x16x32_f16(af0, qf[qt][0], Zero, 0, 0, 0);
      stA[mt][qt] = __builtin_amdgcn_mfma_f32_16x16x32_f16(af1, qf[qt][1], stA[mt][qt], 0, 0, 0);
    }
  }

  int rc = 0;                      // ring slot of kt
  auto step = [&](int kt, f32x4 (&stOld)[4][4], f32x4 (&stNew)[4][4]) {
    __syncthreads();               // K/V(kt+1) published; all waves past iter kt-1 reads
    const int rn = (rc == 2) ? 0 : rc + 1;       // (kt+1) % 3
    if (kt < 30) {
      const int rs = rc ? rc - 1 : 2;            // (kt+2) % 3
      stage(kt + 2, rs);
    }
    f16x4 pb[4][4];
#pragma unroll
    for (int mt = 0; mt < 4; ++mt) {
      // exp2+pack chunk mt of kt (consumes stOld[mt] -> regs die)
#pragma unroll
      for (int qt = 0; qt < 4; ++qt) {
        float e0 = __builtin_amdgcn_exp2f(stOld[mt][qt][0]);
        float e1 = __builtin_amdgcn_exp2f(stOld[mt][qt][1]);
        float e2 = __builtin_amdgcn_exp2f(stOld[mt][qt][2]);
        float e3 = __builtin_amdgcn_exp2f(stOld[mt][qt][3]);
        lsum4[qt] += (f32x4){e0, e1, e2, e3};
        f16x2 p01 = __builtin_bit_cast(f16x2, __builtin_amdgcn_cvt_pkrtz(e0, e1));
        f16x2 p23 = __builtin_bit_cast(f16x2, __builtin_amdgcn_cvt_pkrtz(e2, e3));
        pb[mt][qt] = __builtin_shufflevector(p01, p23, 0, 1, 2, 3);
      }
      // QK tile mt of kt+1 (produces stNew[mt] -> regs born; overlaps exp VALU)
      if (kt < 31) {
        f16x8 af0 = *(const f16x8*)(&Ks[rn][koff[0] + mt * 1024]);
        f16x8 af1 = *(const f16x8*)(&Ks[rn][koff[1] + mt * 1024]);
#pragma unroll
        for (int qt = 0; qt < 4; ++qt) {
          stNew[mt][qt] = __builtin_amdgcn_mfma_f32_16x16x32_f16(af0, qf[qt][0], Zero, 0, 0, 0);
          stNew[mt][qt] = __builtin_amdgcn_mfma_f32_16x16x32_f16(af1, qf[qt][1], stNew[mt][qt], 0, 0, 0);
        }
      }
    }
    // PV(kt): O^T += V^T·P^T from Vs[rc]
#pragma unroll
    for (int half = 0; half < 2; ++half)
#pragma unroll
      for (int mtv = 0; mtv < 4; ++mtv) {
        f16x8 v8 = *(const f16x8*)(&Vs[rc][voff2[half] + mtv * 1024]);
        f16x4 vaA = __builtin_shufflevector(v8, v8, 0, 1, 2, 3);
        f16x4 vaB = __builtin_shufflevector(v8, v8, 4, 5, 6, 7);
#pragma unroll
        for (int qt = 0; qt < 4; ++qt) {
          o[mtv][qt] = __builtin_amdgcn_mfma_f32_16x16x16f16(vaA, pb[half * 2][qt], o[mtv][qt], 0, 0, 0);
          o[mtv][qt] = __builtin_amdgcn_mfma_f32_16x16x16f16(vaB, pb[half * 2 + 1][qt], o[mtv][qt], 0, 0, 0);
        }
      }
    rc = rn;
  };

  for (int ih = 0; ih < 16; ++ih) {
    step(2 * ih,     stA, stB);    // even kt: consume stA, produce stB
    step(2 * ih + 1, stB, stA);    // odd kt:  consume stB, produce stA
  }

  // epilogue: horizontal + cross-quad l reduce, normalize, store
#pragma unroll
  for (int qt = 0; qt < 4; ++qt) {
    float l = (lsum4[qt][0] + lsum4[qt][1]) + (lsum4[qt][2] + lsum4[qt][3]);
    l += __shfl_xor(l, 16, 64);
    l += __shfl_xor(l, 32, 64);
    float inv = 1.f / l;
    int sq = s0 + w * 64 + qt * 16 + l15;
    float* obase = out + ((size_t)b * SEQ + sq) * D_MODEL + h * DH;
#pragma unroll
    for (int mt = 0; mt < 4; ++mt) {
      f32x4 vv;
#pragma unroll
      for (int r = 0; r < 4; ++r) vv[r] = o[mt][qt][r] * inv;
      *(f32x4*)(obase + mt * 16 + quad * 4) = vv;
    }
  }
}

extern "C" void kernel_launch(void* const* d_in, const int* in_sizes, int n_in,
                              void* d_out, int out_size, void* d_ws, size_t ws_size,
                              hipStream_t stream) {
  const float* x  = (const float*)d_in[0];
  const float* Wq = (const float*)d_in[1];
  const float* bq = (const float*)d_in[2];
  const float* Wk = (const float*)d_in[3];
  const float* bk = (const float*)d_in[4];
  const float* Wv = (const float*)d_in[5];
  const float* bv = (const float*)d_in[6];
  float* out = (float*)d_out;

  char* ws = (char*)d_ws;
  f16* xb = (f16*)ws;
  f16* wt = (f16*)(ws + (size_t)16 * 1024 * 1024);
  f16* q  = (f16*)(ws + (size_t)22 * 1024 * 1024);
  f16* kk = q + (size_t)BATCH * SEQ * D_MODEL;
  f16* vt = kk + (size_t)BATCH * SEQ * D_MODEL;

  prep_kernel<<<8192 + 768, 256, 0, stream>>>(x, Wq, Wk, Wv, xb, wt);
  qkv_gemm_kernel<<<1536, 256, 0, stream>>>(xb, wt, bq, bk, bv, q, kk, vt);
  attn_kernel<<<dim3(64, 8), 256, 0, stream>>>(q, kk, vt, out);
}

// Round 11
// 247.050 us; speedup vs baseline: 1.0499x; 1.0499x over previous
//
#include <hip/hip_runtime.h>

typedef _Float16 f16;
typedef __attribute__((ext_vector_type(2))) _Float16 f16x2;
typedef __attribute__((ext_vector_type(2))) __fp16   hf16x2;  // cvt_pkrtz native return
typedef __attribute__((ext_vector_type(4))) _Float16 f16x4;
typedef __attribute__((ext_vector_type(8))) _Float16 f16x8;
typedef __attribute__((ext_vector_type(4))) float    f32x4;

#define D_MODEL 1024
#define HEADS   16
#define DH      64
#define SEQ     2048
#define BATCH   4
#define SSCALE  0.1803368801111204f   // 1/sqrt(64) * log2(e)

// async 16B global->LDS; lds dst is wave-uniform base + lane*16
__device__ __forceinline__ void gload_lds16(const void* g, void* lds) {
  __builtin_amdgcn_global_load_lds(
      (const __attribute__((address_space(1))) unsigned int*)g,
      (__attribute__((address_space(3))) unsigned int*)lds, 16, 0, 0);
}

// ---------------- prep: cast x, transpose W (merged: one dispatch; r0 form) ----------------
__global__ __launch_bounds__(256) void prep_kernel(const float* __restrict__ x,
                                                   const float* __restrict__ Wq,
                                                   const float* __restrict__ Wk,
                                                   const float* __restrict__ Wv,
                                                   f16* __restrict__ xb,
                                                   f16* __restrict__ wt) {
  if (blockIdx.x < 8192) {                     // cast x fp32 -> f16
    int i = blockIdx.x * 256 + threadIdx.x;
    float4 v = ((const float4*)x)[i];
    f16x4 h;
    h[0] = (f16)v.x; h[1] = (f16)v.y; h[2] = (f16)v.z; h[3] = (f16)v.w;
    ((f16x4*)xb)[i] = h;
    return;
  }
  int bid = blockIdx.x - 8192;                 // W [K][N] fp32 -> Wt [N][K] f16
  int z = bid >> 8, rem = bid & 255;
  const float* W = z == 0 ? Wq : (z == 1 ? Wk : Wv);
  f16* out = wt + (size_t)z * D_MODEL * D_MODEL;
  __shared__ float tile[64][65];
  int n0 = (rem & 15) * 64, k0 = (rem >> 4) * 64;
  int tx = threadIdx.x & 63, ty = threadIdx.x >> 6;
#pragma unroll
  for (int r = 0; r < 16; ++r)
    tile[ty * 16 + r][tx] = W[(size_t)(k0 + ty * 16 + r) * D_MODEL + n0 + tx];
  __syncthreads();
#pragma unroll
  for (int r = 0; r < 16; ++r)
    out[(size_t)(n0 + ty * 16 + r) * D_MODEL + k0 + tx] = (f16)tile[tx][ty * 16 + r];
}

// ---------------- QKV projection GEMM (r4 verbatim: 69.5us measured best) ----------------
// 128x128 tile, BK=32, ring-3 LDS + counted vmcnt(4). XCD-locality remap:
// XCD j (= bid%8) owns a contiguous m-band (y' = j*8 + t%8) -> per-XCD L2
// working set = 2MB xb band + 2MB wt(z). Bijective over 1536 blocks.
__global__ __launch_bounds__(256, 3) void qkv_gemm_kernel(
    const f16* __restrict__ xb, const f16* __restrict__ wt_all,
    const float* __restrict__ bq, const float* __restrict__ bk, const float* __restrict__ bv,
    f16* __restrict__ qout, f16* __restrict__ kout, f16* __restrict__ vtout) {
  const int bid = blockIdx.x;
  const int j = bid & 7, t = bid >> 3;
  const int by = j * 8 + (t & 7);            // m-block: contiguous band per XCD
  const int bx = (t >> 3) & 7;               // n-block
  const int z  = t >> 6;                     // q/k/v
  const f16* wt = wt_all + (size_t)z * D_MODEL * D_MODEL;
  const float* bias = z == 0 ? bq : (z == 1 ? bk : bv);
  const int n0 = bx * 128, m0 = by * 128;

  __shared__ f16 As[3][128 * 32];   // 8KB per buffer, ring-3
  __shared__ f16 Bs[3][128 * 32];   // 48KB total -> still 3 blocks/CU

  const int tid = threadIdx.x;
  const int lane = tid & 63, w = tid >> 6;
  const int quad = lane >> 4, l15 = lane & 15;
  const int wm = w & 1, wn = w >> 1;

  const int pce = (quad ^ ((l15 >> 1) & 3)) * 8;
  const int aoff = wm * 2048 + l15 * 32 + pce;
  const int boff = wn * 2048 + l15 * 32 + pce;

  int srow[2], scl[2];
#pragma unroll
  for (int c = 0; c < 2; ++c) {
    int slot = (w * 2 + c) * 64 + lane;
    srow[c] = slot >> 2;
    scl[c] = (slot & 3) ^ ((srow[c] >> 1) & 3);
  }

  f32x4 acc[4][4];
#pragma unroll
  for (int i = 0; i < 4; ++i)
#pragma unroll
    for (int jj = 0; jj < 4; ++jj) acc[i][jj] = (f32x4){0.f, 0.f, 0.f, 0.f};

  // prologue: stage k-tiles 0 and 1 (issue order: tile0's 4 loads, tile1's 4)
#pragma unroll
  for (int tt = 0; tt < 2; ++tt)
#pragma unroll
    for (int c = 0; c < 2; ++c) {
      gload_lds16(xb + (size_t)(m0 + srow[c]) * D_MODEL + tt * 32 + scl[c] * 8, &As[tt][(w * 2 + c) * 512]);
      gload_lds16(wt + (size_t)(n0 + srow[c]) * D_MODEL + tt * 32 + scl[c] * 8, &Bs[tt][(w * 2 + c) * 512]);
    }

  f16x8 aP[4], bP[4];
  int buf = 0;
  for (int it = 0; it < 32; ++it) {
    // retire through this iter's tile; keep next tile's loads airborne
    if (it == 31) { asm volatile("s_waitcnt vmcnt(0)" ::: "memory"); }
    else          { asm volatile("s_waitcnt vmcnt(4)" ::: "memory"); }
    __builtin_amdgcn_s_barrier();
    __builtin_amdgcn_sched_barrier(0);        // pin: nothing crosses the barrier
    if (it < 30) {
      const int sb = buf ? buf - 1 : 2;       // (it+2) % 3
      const int kn = (it + 2) * 32;
#pragma unroll
      for (int c = 0; c < 2; ++c) {
        gload_lds16(xb + (size_t)(m0 + srow[c]) * D_MODEL + kn + scl[c] * 8, &As[sb][(w * 2 + c) * 512]);
        gload_lds16(wt + (size_t)(n0 + srow[c]) * D_MODEL + kn + scl[c] * 8, &Bs[sb][(w * 2 + c) * 512]);
      }
    }
    f16x8 aC[4], bC[4];
#pragma unroll
    for (int mt = 0; mt < 4; ++mt) aC[mt] = *(const f16x8*)(&As[buf][aoff + mt * 512]);
#pragma unroll
    for (int nt = 0; nt < 4; ++nt) bC[nt] = *(const f16x8*)(&Bs[buf][boff + nt * 512]);
    if (it) {
#pragma unroll
      for (int mt = 0; mt < 4; ++mt)
#pragma unroll
        for (int nt = 0; nt < 4; ++nt)
          acc[mt][nt] = __builtin_amdgcn_mfma_f32_16x16x32_f16(aP[mt], bP[nt], acc[mt][nt], 0, 0, 0);
    }
#pragma unroll
    for (int tt = 0; tt < 4; ++tt) { aP[tt] = aC[tt]; bP[tt] = bC[tt]; }
    buf = (buf == 2) ? 0 : buf + 1;
  }
#pragma unroll
  for (int mt = 0; mt < 4; ++mt)
#pragma unroll
    for (int nt = 0; nt < 4; ++nt)
      acc[mt][nt] = __builtin_amdgcn_mfma_f32_16x16x32_f16(aP[mt], bP[nt], acc[mt][nt], 0, 0, 0);

  const float sc = (z == 0) ? SSCALE : 1.0f;
  float bcol[4];
#pragma unroll
  for (int nt = 0; nt < 4; ++nt) bcol[nt] = bias[n0 + wn * 64 + nt * 16 + l15];

  if (z < 2) {
    f16* out = (z == 0) ? qout : kout;
#pragma unroll
    for (int mt = 0; mt < 4; ++mt) {
      int mbase = m0 + wm * 64 + mt * 16 + quad * 4;
#pragma unroll
      for (int nt = 0; nt < 4; ++nt) {
        int n = n0 + wn * 64 + nt * 16 + l15;
        int h = n >> 6, dh = n & 63;
#pragma unroll
        for (int r = 0; r < 4; ++r) {
          int m = mbase + r;
          int b = m >> 11, s = m & 2047;
          out[((size_t)(b * HEADS + h) * SEQ + s) * DH + dh] = (f16)((acc[mt][nt][r] + bcol[nt]) * sc);
        }
      }
    }
  } else {
    // V in PV-fragment order: per (bh,kt) 4096-elem tile, row dh (64 elems),
    // sk' = quad*16 + mt*4 + r, phys 8-elem chunk = (sk'>>3) ^ (dh&7).
#pragma unroll
    for (int mt = 0; mt < 4; ++mt) {
      int mbase = m0 + wm * 64 + mt * 16 + quad * 4;
      int b = mbase >> 11, seq = mbase & 2047;
      int kt = seq >> 6;
#pragma unroll
      for (int nt = 0; nt < 4; ++nt) {
        int n = n0 + wn * 64 + nt * 16 + l15;
        int h = n >> 6, dh = n & 63;
        f16x4 v;
#pragma unroll
        for (int r = 0; r < 4; ++r) v[r] = (f16)(acc[mt][nt][r] + bcol[nt]);
        int phys = (quad * 2 + (mt >> 1)) ^ (dh & 7);
        size_t off = (((size_t)(b * HEADS + h) * 32 + kt) * 4096) + dh * 64 + phys * 8 + (mt & 1) * 4;
        *(f16x4*)(vtout + off) = v;
      }
    }
  }
}

// ---------------- fused flash attention: r9 config (best total) + T5 setprio ----------------
// 2-wave blocks / BQ=128: grid (64,16) = 1024 blocks = 4 independent barrier
// domains/CU (8 waves/CU, 64 q/wave). NEW vs r9: s_setprio(1) wraps the QK
// and PV MFMA clusters — pays exactly in this regime (SIMD's 2 waves come
// from different blocks, drift out of phase; MFMA-entering wave preempts the
// exp2-issuing wave's round-robin slot). Zero structural/register change.
__global__ __launch_bounds__(128, 2) void attn_kernel(
    const f16* __restrict__ q, const f16* __restrict__ k, const f16* __restrict__ vt,
    float* __restrict__ out) {
  const int bh = blockIdx.x;             // (bh, qtile): q-tiles of one head share an XCD
  const int s0 = blockIdx.y * 128;
  const int b = bh >> 4, h = bh & 15;
  const int tid = threadIdx.x, lane = tid & 63, w = tid >> 6;   // w in {0,1}
  const int quad = lane >> 4, l15 = lane & 15;

  __shared__ f16 Ks[2][64 * 64];   // [sk][dh], 8KB per buffer
  __shared__ f16 Vs[2][64 * 64];   // PV-fragment order, 8KB per buffer

  const f16* qbase = q + ((size_t)bh * SEQ + s0 + w * 64) * DH;
  const f16* kbase = k + (size_t)bh * SEQ * DH;
  const f16* vbase = vt + (size_t)bh * DH * SEQ;   // tile kt at +kt*4096

  // Q fragments: 4 q-subtiles of 16 per wave
  f16x8 qf[4][2];
#pragma unroll
  for (int qt = 0; qt < 4; ++qt)
#pragma unroll
    for (int ks = 0; ks < 2; ++ks)
      qf[qt][ks] = *(const f16x8*)(qbase + (qt * 16 + l15) * DH + ks * 32 + quad * 8);

  int koff[2];
  koff[0] = l15 * 64 + ((quad ^ (l15 & 7)) * 8);
  koff[1] = l15 * 64 + (((4 + quad) ^ (l15 & 7)) * 8);
  int voff2[2];                    // V b128 reads: half h covers ks=2h,2h+1
  voff2[0] = l15 * 64 + (((quad * 2) ^ (l15 & 7)) * 8);
  voff2[1] = l15 * 64 + (((quad * 2 + 1) ^ (l15 & 7)) * 8);

  int srow[4], scl[4];             // K staging swizzle: 4 calls/thread (128 thr)
#pragma unroll
  for (int c = 0; c < 4; ++c) {
    int slot = (w * 4 + c) * 64 + lane;
    srow[c] = slot >> 3;
    scl[c] = (slot & 7) ^ (srow[c] & 7);
  }
  int vslot[4];                    // identity V staging offsets: 4 calls/thread
#pragma unroll
  for (int c = 0; c < 4; ++c) vslot[c] = ((w * 4 + c) * 64 + lane) * 8;

  f32x4 lsum4[4];
#pragma unroll
  for (int qt = 0; qt < 4; ++qt) lsum4[qt] = (f32x4){0.f, 0.f, 0.f, 0.f};
  f32x4 o[4][4];
#pragma unroll
  for (int i = 0; i < 4; ++i)
#pragma unroll
    for (int jj = 0; jj < 4; ++jj) o[i][jj] = (f32x4){0.f, 0.f, 0.f, 0.f};
  const f32x4 Zero = (f32x4){0.f, 0.f, 0.f, 0.f};

  // prologue: stage kt=0 into buf 0
#pragma unroll
  for (int c = 0; c < 4; ++c)
    gload_lds16(kbase + (size_t)srow[c] * DH + scl[c] * 8, &Ks[0][(w * 4 + c) * 512]);
#pragma unroll
  for (int c = 0; c < 4; ++c)
    gload_lds16(vbase + vslot[c], &Vs[0][(w * 4 + c) * 512]);

  for (int kt = 0; kt < SEQ / 64; ++kt) {
    const int buf = kt & 1;
    __syncthreads();                          // this iter's tiles ready (staged last iter)
    if (kt < SEQ / 64 - 1) {
      const int kn = (kt + 1) * 64;
#pragma unroll
      for (int c = 0; c < 4; ++c)
        gload_lds16(kbase + (size_t)(kn + srow[c]) * DH + scl[c] * 8, &Ks[buf ^ 1][(w * 4 + c) * 512]);
#pragma unroll
      for (int c = 0; c < 4; ++c)
        gload_lds16(vbase + (kt + 1) * 4096 + vslot[c], &Vs[buf ^ 1][(w * 4 + c) * 512]);
    }

    // S^T = K·Q^T (Q pre-scaled into log2 domain); 4 sk-tiles x 4 q-tiles
    f32x4 st[4][4];
#pragma unroll
    for (int mt = 0; mt < 4; ++mt) {
      f16x8 af0 = *(const f16x8*)(&Ks[buf][koff[0] + mt * 1024]);
      f16x8 af1 = *(const f16x8*)(&Ks[buf][koff[1] + mt * 1024]);
      __builtin_amdgcn_s_setprio(1);
#pragma unroll
      for (int qt = 0; qt < 4; ++qt) {
        st[mt][qt] = __builtin_amdgcn_mfma_f32_16x16x32_f16(af0, qf[qt][0], Zero, 0, 0, 0);
        st[mt][qt] = __builtin_amdgcn_mfma_f32_16x16x32_f16(af1, qf[qt][1], st[mt][qt], 0, 0, 0);
      }
      __builtin_amdgcn_s_setprio(0);
    }

    // exp2 + pack all 4 ks-chunks; lsum accumulated as f32x4 vector
    f16x4 pb[4][4];
#pragma unroll
    for (int ks = 0; ks < 4; ++ks)
#pragma unroll
      for (int qt = 0; qt < 4; ++qt) {
        float e0 = __builtin_amdgcn_exp2f(st[ks][qt][0]);
        float e1 = __builtin_amdgcn_exp2f(st[ks][qt][1]);
        float e2 = __builtin_amdgcn_exp2f(st[ks][qt][2]);
        float e3 = __builtin_amdgcn_exp2f(st[ks][qt][3]);
        f32x4 ev = (f32x4){e0, e1, e2, e3};
        lsum4[qt] += ev;
        f16x2 p01 = __builtin_bit_cast(f16x2, __builtin_amdgcn_cvt_pkrtz(e0, e1));
        f16x2 p23 = __builtin_bit_cast(f16x2, __builtin_amdgcn_cvt_pkrtz(e2, e3));
        pb[ks][qt] = __builtin_shufflevector(p01, p23, 0, 1, 2, 3);
      }

    // PV: O^T += V^T·P^T. One b128 per (half,mt) feeds 2 K=16 MFMAs x 4 qt.
#pragma unroll
    for (int half = 0; half < 2; ++half)
#pragma unroll
      for (int mt = 0; mt < 4; ++mt) {
        f16x8 v8 = *(const f16x8*)(&Vs[buf][voff2[half] + mt * 1024]);
        f16x4 vaA = __builtin_shufflevector(v8, v8, 0, 1, 2, 3);
        f16x4 vaB = __builtin_shufflevector(v8, v8, 4, 5, 6, 7);
        __builtin_amdgcn_s_setprio(1);
#pragma unroll
        for (int qt = 0; qt < 4; ++qt) {
          o[mt][qt] = __builtin_amdgcn_mfma_f32_16x16x16f16(vaA, pb[half * 2][qt], o[mt][qt], 0, 0, 0);
          o[mt][qt] = __builtin_amdgcn_mfma_f32_16x16x16f16(vaB, pb[half * 2 + 1][qt], o[mt][qt], 0, 0, 0);
        }
        __builtin_amdgcn_s_setprio(0);
      }
  }

  // epilogue: horizontal + cross-quad l reduce, normalize, store
#pragma unroll
  for (int qt = 0; qt < 4; ++qt) {
    float l = (lsum4[qt][0] + lsum4[qt][1]) + (lsum4[qt][2] + lsum4[qt][3]);
    l += __shfl_xor(l, 16, 64);
    l += __shfl_xor(l, 32, 64);
    float inv = 1.f / l;
    int sq = s0 + w * 64 + qt * 16 + l15;
    float* obase = out + ((size_t)b * SEQ + sq) * D_MODEL + h * DH;
#pragma unroll
    for (int mt = 0; mt < 4; ++mt) {
      f32x4 vv;
#pragma unroll
      for (int r = 0; r < 4; ++r) vv[r] = o[mt][qt][r] * inv;
      *(f32x4*)(obase + mt * 16 + quad * 4) = vv;
    }
  }
}

extern "C" void kernel_launch(void* const* d_in, const int* in_sizes, int n_in,
                              void* d_out, int out_size, void* d_ws, size_t ws_size,
                              hipStream_t stream) {
  const float* x  = (const float*)d_in[0];
  const float* Wq = (const float*)d_in[1];
  const float* bq = (const float*)d_in[2];
  const float* Wk = (const float*)d_in[3];
  const float* bk = (const float*)d_in[4];
  const float* Wv = (const float*)d_in[5];
  const float* bv = (const float*)d_in[6];
  float* out = (float*)d_out;

  char* ws = (char*)d_ws;
  f16* xb = (f16*)ws;
  f16* wt = (f16*)(ws + (size_t)16 * 1024 * 1024);
  f16* q  = (f16*)(ws + (size_t)22 * 1024 * 1024);
  f16* kk = q + (size_t)BATCH * SEQ * D_MODEL;
  f16* vt = kk + (size_t)BATCH * SEQ * D_MODEL;

  prep_kernel<<<8192 + 768, 256, 0, stream>>>(x, Wq, Wk, Wv, xb, wt);
  qkv_gemm_kernel<<<1536, 256, 0, stream>>>(xb, wt, bq, bk, bv, q, kk, vt);
  attn_kernel<<<dim3(64, 16), 128, 0, stream>>>(q, kk, vt, out);
}

// Round 12
// 239.665 us; speedup vs baseline: 1.0823x; 1.0308x over previous
//
#include <hip/hip_runtime.h>

typedef _Float16 f16;
typedef __attribute__((ext_vector_type(2))) _Float16 f16x2;
typedef __attribute__((ext_vector_type(2))) __fp16   hf16x2;  // cvt_pkrtz native return
typedef __attribute__((ext_vector_type(4))) _Float16 f16x4;
typedef __attribute__((ext_vector_type(8))) _Float16 f16x8;
typedef __attribute__((ext_vector_type(4))) float    f32x4;
typedef __attribute__((ext_vector_type(16))) float   f32x16;
typedef __attribute__((ext_vector_type(4))) unsigned u32x4;

#define D_MODEL 1024
#define HEADS   16
#define DH      64
#define SEQ     2048
#define BATCH   4
#define SSCALE  0.1803368801111204f   // 1/sqrt(64) * log2(e)

// async 16B global->LDS; lds dst is wave-uniform base + lane*16
__device__ __forceinline__ void gload_lds16(const void* g, void* lds) {
  __builtin_amdgcn_global_load_lds(
      (const __attribute__((address_space(1))) unsigned int*)g,
      (__attribute__((address_space(3))) unsigned int*)lds, 16, 0, 0);
}

// ---------------- prep: cast x, transpose W (merged: one dispatch; r0 form) ----------------
__global__ __launch_bounds__(256) void prep_kernel(const float* __restrict__ x,
                                                   const float* __restrict__ Wq,
                                                   const float* __restrict__ Wk,
                                                   const float* __restrict__ Wv,
                                                   f16* __restrict__ xb,
                                                   f16* __restrict__ wt) {
  if (blockIdx.x < 8192) {                     // cast x fp32 -> f16
    int i = blockIdx.x * 256 + threadIdx.x;
    float4 v = ((const float4*)x)[i];
    f16x4 h;
    h[0] = (f16)v.x; h[1] = (f16)v.y; h[2] = (f16)v.z; h[3] = (f16)v.w;
    ((f16x4*)xb)[i] = h;
    return;
  }
  int bid = blockIdx.x - 8192;                 // W [K][N] fp32 -> Wt [N][K] f16
  int z = bid >> 8, rem = bid & 255;
  const float* W = z == 0 ? Wq : (z == 1 ? Wk : Wv);
  f16* out = wt + (size_t)z * D_MODEL * D_MODEL;
  __shared__ float tile[64][65];
  int n0 = (rem & 15) * 64, k0 = (rem >> 4) * 64;
  int tx = threadIdx.x & 63, ty = threadIdx.x >> 6;
#pragma unroll
  for (int r = 0; r < 16; ++r)
    tile[ty * 16 + r][tx] = W[(size_t)(k0 + ty * 16 + r) * D_MODEL + n0 + tx];
  __syncthreads();
#pragma unroll
  for (int r = 0; r < 16; ++r)
    out[(size_t)(n0 + ty * 16 + r) * D_MODEL + k0 + tx] = (f16)tile[tx][ty * 16 + r];
}

// ---------------- QKV projection GEMM (r4 structure: 69.5us measured best) ----------------
// 128x128 tile, BK=32, ring-3 LDS + counted vmcnt(4). XCD-locality remap.
// V epilogue: TRUE-sk fragment order for the new 32x32 attn PV:
//   elem (sk, dh) at tile + dh*64 + ((sk>>3) ^ (dh&7))*8 + (sk&7)
//   sk = mt*16 + quad*4 + r  ->  phys = (mt*2 + (quad>>1)) ^ (dh&7), inner (quad&1)*4
__global__ __launch_bounds__(256, 3) void qkv_gemm_kernel(
    const f16* __restrict__ xb, const f16* __restrict__ wt_all,
    const float* __restrict__ bq, const float* __restrict__ bk, const float* __restrict__ bv,
    f16* __restrict__ qout, f16* __restrict__ kout, f16* __restrict__ vtout) {
  const int bid = blockIdx.x;
  const int j = bid & 7, t = bid >> 3;
  const int by = j * 8 + (t & 7);            // m-block: contiguous band per XCD
  const int bx = (t >> 3) & 7;               // n-block
  const int z  = t >> 6;                     // q/k/v
  const f16* wt = wt_all + (size_t)z * D_MODEL * D_MODEL;
  const float* bias = z == 0 ? bq : (z == 1 ? bk : bv);
  const int n0 = bx * 128, m0 = by * 128;

  __shared__ f16 As[3][128 * 32];   // 8KB per buffer, ring-3
  __shared__ f16 Bs[3][128 * 32];   // 48KB total -> still 3 blocks/CU

  const int tid = threadIdx.x;
  const int lane = tid & 63, w = tid >> 6;
  const int quad = lane >> 4, l15 = lane & 15;
  const int wm = w & 1, wn = w >> 1;

  const int pce = (quad ^ ((l15 >> 1) & 3)) * 8;
  const int aoff = wm * 2048 + l15 * 32 + pce;
  const int boff = wn * 2048 + l15 * 32 + pce;

  int srow[2], scl[2];
#pragma unroll
  for (int c = 0; c < 2; ++c) {
    int slot = (w * 2 + c) * 64 + lane;
    srow[c] = slot >> 2;
    scl[c] = (slot & 3) ^ ((srow[c] >> 1) & 3);
  }

  f32x4 acc[4][4];
#pragma unroll
  for (int i = 0; i < 4; ++i)
#pragma unroll
    for (int jj = 0; jj < 4; ++jj) acc[i][jj] = (f32x4){0.f, 0.f, 0.f, 0.f};

  // prologue: stage k-tiles 0 and 1
#pragma unroll
  for (int tt = 0; tt < 2; ++tt)
#pragma unroll
    for (int c = 0; c < 2; ++c) {
      gload_lds16(xb + (size_t)(m0 + srow[c]) * D_MODEL + tt * 32 + scl[c] * 8, &As[tt][(w * 2 + c) * 512]);
      gload_lds16(wt + (size_t)(n0 + srow[c]) * D_MODEL + tt * 32 + scl[c] * 8, &Bs[tt][(w * 2 + c) * 512]);
    }

  f16x8 aP[4], bP[4];
  int buf = 0;
  for (int it = 0; it < 32; ++it) {
    if (it == 31) { asm volatile("s_waitcnt vmcnt(0)" ::: "memory"); }
    else          { asm volatile("s_waitcnt vmcnt(4)" ::: "memory"); }
    __builtin_amdgcn_s_barrier();
    __builtin_amdgcn_sched_barrier(0);        // pin: nothing crosses the barrier
    if (it < 30) {
      const int sb = buf ? buf - 1 : 2;       // (it+2) % 3
      const int kn = (it + 2) * 32;
#pragma unroll
      for (int c = 0; c < 2; ++c) {
        gload_lds16(xb + (size_t)(m0 + srow[c]) * D_MODEL + kn + scl[c] * 8, &As[sb][(w * 2 + c) * 512]);
        gload_lds16(wt + (size_t)(n0 + srow[c]) * D_MODEL + kn + scl[c] * 8, &Bs[sb][(w * 2 + c) * 512]);
      }
    }
    f16x8 aC[4], bC[4];
#pragma unroll
    for (int mt = 0; mt < 4; ++mt) aC[mt] = *(const f16x8*)(&As[buf][aoff + mt * 512]);
#pragma unroll
    for (int nt = 0; nt < 4; ++nt) bC[nt] = *(const f16x8*)(&Bs[buf][boff + nt * 512]);
    if (it) {
#pragma unroll
      for (int mt = 0; mt < 4; ++mt)
#pragma unroll
        for (int nt = 0; nt < 4; ++nt)
          acc[mt][nt] = __builtin_amdgcn_mfma_f32_16x16x32_f16(aP[mt], bP[nt], acc[mt][nt], 0, 0, 0);
    }
#pragma unroll
    for (int tt = 0; tt < 4; ++tt) { aP[tt] = aC[tt]; bP[tt] = bC[tt]; }
    buf = (buf == 2) ? 0 : buf + 1;
  }
#pragma unroll
  for (int mt = 0; mt < 4; ++mt)
#pragma unroll
    for (int nt = 0; nt < 4; ++nt)
      acc[mt][nt] = __builtin_amdgcn_mfma_f32_16x16x32_f16(aP[mt], bP[nt], acc[mt][nt], 0, 0, 0);

  const float sc = (z == 0) ? SSCALE : 1.0f;
  float bcol[4];
#pragma unroll
  for (int nt = 0; nt < 4; ++nt) bcol[nt] = bias[n0 + wn * 64 + nt * 16 + l15];

  if (z < 2) {
    f16* out = (z == 0) ? qout : kout;
#pragma unroll
    for (int mt = 0; mt < 4; ++mt) {
      int mbase = m0 + wm * 64 + mt * 16 + quad * 4;
#pragma unroll
      for (int nt = 0; nt < 4; ++nt) {
        int n = n0 + wn * 64 + nt * 16 + l15;
        int h = n >> 6, dh = n & 63;
#pragma unroll
        for (int r = 0; r < 4; ++r) {
          int m = mbase + r;
          int b = m >> 11, s = m & 2047;
          out[((size_t)(b * HEADS + h) * SEQ + s) * DH + dh] = (f16)((acc[mt][nt][r] + bcol[nt]) * sc);
        }
      }
    }
  } else {
    // V in TRUE-sk fragment order: sk = mt*16 + quad*4 + r, dh = n&63
    // addr = tile + dh*64 + ((sk>>3)^(dh&7))*8 + (sk&7)
#pragma unroll
    for (int mt = 0; mt < 4; ++mt) {
      int mbase = m0 + wm * 64 + mt * 16 + quad * 4;
      int b = mbase >> 11, seq = mbase & 2047;
      int kt = seq >> 6;
#pragma unroll
      for (int nt = 0; nt < 4; ++nt) {
        int n = n0 + wn * 64 + nt * 16 + l15;
        int h = n >> 6, dh = n & 63;
        f16x4 v;
#pragma unroll
        for (int r = 0; r < 4; ++r) v[r] = (f16)(acc[mt][nt][r] + bcol[nt]);
        int phys = (mt * 2 + (quad >> 1)) ^ (dh & 7);
        size_t off = (((size_t)(b * HEADS + h) * 32 + kt) * 4096) + dh * 64 + phys * 8 + (quad & 1) * 4;
        *(f16x4*)(vtout + off) = v;
      }
    }
  }
}

// ---------------- fused flash attention: full-rate 32x32x16 MFMAs ----------------
// r9 geometry (2-wave blocks, BQ=128, dbuf-2, grid 64x16 = 4 blocks/CU).
// PV previously used legacy 16x16x16 (half-rate on gfx950: same pipe cycles,
// half FLOPs). Now QK and PV both use full-rate 32x32x16:
//  - QK: S^T tiles (skhalf, qhalf) 32x32, A = K rows (8-dh contiguous, same
//    swizzled Ks layout; only read offsets changed), B = Q frags.
//  - P repack 4-granular -> 8-granular is exactly the lane<32<->lane>=32
//    exchange: v_permlane32_swap_b32 (T12). 8 cvt_pk + 4 swaps per tile.
//  - PV: O^T tiles (dhhalf, qhalf), A = V^T (8-sk contiguous via new true-sk
//    V layout), B = packed P.
// Matrix-pipe time per wave-kt: 1861 -> 1024 cyc.
__global__ __launch_bounds__(128, 2) void attn_kernel(
    const f16* __restrict__ q, const f16* __restrict__ k, const f16* __restrict__ vt,
    float* __restrict__ out) {
  const int bh = blockIdx.x;             // (bh, qtile): q-tiles of one head share an XCD
  const int s0 = blockIdx.y * 128;
  const int b = bh >> 4, h = bh & 15;
  const int tid = threadIdx.x, lane = tid & 63, w = tid >> 6;   // w in {0,1}
  const int l31 = lane & 31, hi = lane >> 5;

  __shared__ f16 Ks[2][64 * 64];   // [sk][dh], chunk^(row&7) swizzle, 8KB/buf
  __shared__ f16 Vs[2][64 * 64];   // true-sk fragment order, 8KB/buf

  const f16* kbase = k + (size_t)bh * SEQ * DH;
  const f16* vbase = vt + (size_t)bh * DH * SEQ;   // tile kt at +kt*4096

  // Q fragments: B-operand n = l31 (q row), k = hi*8+j (dh)
  f16x8 qg[2][4];
#pragma unroll
  for (int qh = 0; qh < 2; ++qh)
#pragma unroll
    for (int ks = 0; ks < 4; ++ks)
      qg[qh][ks] = *(const f16x8*)(q + ((size_t)bh * SEQ + s0 + w * 64 + qh * 32 + l31) * DH + ks * 16 + hi * 8);

  int srow[4], scl[4];             // K staging swizzle: chunk ^ (row&7)
#pragma unroll
  for (int c = 0; c < 4; ++c) {
    int slot = (w * 4 + c) * 64 + lane;
    srow[c] = slot >> 3;
    scl[c] = (slot & 7) ^ (srow[c] & 7);
  }
  int vslot[4];                    // identity V staging (swizzle baked by producer)
#pragma unroll
  for (int c = 0; c < 4; ++c) vslot[c] = ((w * 4 + c) * 64 + lane) * 8;

  float lsum[2] = {0.f, 0.f};
  f32x16 o[2][2];                  // [dhhalf][qhalf]
#pragma unroll
  for (int i = 0; i < 2; ++i)
#pragma unroll
    for (int jj = 0; jj < 2; ++jj)
#pragma unroll
      for (int e = 0; e < 16; ++e) o[i][jj][e] = 0.f;
  f32x16 Zero;
#pragma unroll
  for (int e = 0; e < 16; ++e) Zero[e] = 0.f;

  // prologue: stage kt=0 into buf 0
#pragma unroll
  for (int c = 0; c < 4; ++c)
    gload_lds16(kbase + (size_t)srow[c] * DH + scl[c] * 8, &Ks[0][(w * 4 + c) * 512]);
#pragma unroll
  for (int c = 0; c < 4; ++c)
    gload_lds16(vbase + vslot[c], &Vs[0][(w * 4 + c) * 512]);

  for (int kt = 0; kt < SEQ / 64; ++kt) {
    const int buf = kt & 1;
    __syncthreads();                          // this iter's tiles ready (staged last iter)
    if (kt < SEQ / 64 - 1) {
      const int kn = (kt + 1) * 64;
#pragma unroll
      for (int c = 0; c < 4; ++c)
        gload_lds16(kbase + (size_t)(kn + srow[c]) * DH + scl[c] * 8, &Ks[buf ^ 1][(w * 4 + c) * 512]);
#pragma unroll
      for (int c = 0; c < 4; ++c)
        gload_lds16(vbase + (kt + 1) * 4096 + vslot[c], &Vs[buf ^ 1][(w * 4 + c) * 512]);
    }

#pragma unroll
    for (int skh = 0; skh < 2; ++skh) {
      // ---- QK: S^T (32sk x 32q) x 2 qhalf, K-steps over dh ----
      const int krow = skh * 32 + l31;
      const int krx = krow & 7;
      f32x16 st0 = Zero, st1 = Zero;
#pragma unroll
      for (int ks = 0; ks < 4; ++ks) {
        f16x8 a = *(const f16x8*)(&Ks[buf][krow * 64 + (((ks << 1) | hi) ^ krx) * 8]);
        st0 = __builtin_amdgcn_mfma_f32_32x32x16_f16(a, qg[0][ks], st0, 0, 0, 0);
        st1 = __builtin_amdgcn_mfma_f32_32x32x16_f16(a, qg[1][ks], st1, 0, 0, 0);
      }

      // ---- exp2 + pack (8 cvt_pk + 4 permlane32_swap per qhalf) ----
      f16x8 bop[2][2];             // [ks16][qhalf]
#pragma unroll
      for (int qh = 0; qh < 2; ++qh) {
        const f32x16 stv = qh ? st1 : st0;
        unsigned d0, d1, d2, d3, d4, d5, d6, d7;
        float e0, e1, acc = 0.f;
        e0 = __builtin_amdgcn_exp2f(stv[0]);  e1 = __builtin_amdgcn_exp2f(stv[1]);
        acc += e0 + e1; d0 = __builtin_bit_cast(unsigned, __builtin_amdgcn_cvt_pkrtz(e0, e1));
        e0 = __builtin_amdgcn_exp2f(stv[2]);  e1 = __builtin_amdgcn_exp2f(stv[3]);
        acc += e0 + e1; d1 = __builtin_bit_cast(unsigned, __builtin_amdgcn_cvt_pkrtz(e0, e1));
        e0 = __builtin_amdgcn_exp2f(stv[4]);  e1 = __builtin_amdgcn_exp2f(stv[5]);
        acc += e0 + e1; d2 = __builtin_bit_cast(unsigned, __builtin_amdgcn_cvt_pkrtz(e0, e1));
        e0 = __builtin_amdgcn_exp2f(stv[6]);  e1 = __builtin_amdgcn_exp2f(stv[7]);
        acc += e0 + e1; d3 = __builtin_bit_cast(unsigned, __builtin_amdgcn_cvt_pkrtz(e0, e1));
        e0 = __builtin_amdgcn_exp2f(stv[8]);  e1 = __builtin_amdgcn_exp2f(stv[9]);
        acc += e0 + e1; d4 = __builtin_bit_cast(unsigned, __builtin_amdgcn_cvt_pkrtz(e0, e1));
        e0 = __builtin_amdgcn_exp2f(stv[10]); e1 = __builtin_amdgcn_exp2f(stv[11]);
        acc += e0 + e1; d5 = __builtin_bit_cast(unsigned, __builtin_amdgcn_cvt_pkrtz(e0, e1));
        e0 = __builtin_amdgcn_exp2f(stv[12]); e1 = __builtin_amdgcn_exp2f(stv[13]);
        acc += e0 + e1; d6 = __builtin_bit_cast(unsigned, __builtin_amdgcn_cvt_pkrtz(e0, e1));
        e0 = __builtin_amdgcn_exp2f(stv[14]); e1 = __builtin_amdgcn_exp2f(stv[15]);
        acc += e0 + e1; d7 = __builtin_bit_cast(unsigned, __builtin_amdgcn_cvt_pkrtz(e0, e1));
        lsum[qh] += acc;
        // ks16=0: rows 0-15; ks16=1: rows 16-31 (true sk within the 32-block)
        asm("v_permlane32_swap_b32 %0, %1" : "+v"(d0), "+v"(d2));
        asm("v_permlane32_swap_b32 %0, %1" : "+v"(d1), "+v"(d3));
        asm("v_permlane32_swap_b32 %0, %1" : "+v"(d4), "+v"(d6));
        asm("v_permlane32_swap_b32 %0, %1" : "+v"(d5), "+v"(d7));
        bop[0][qh] = __builtin_bit_cast(f16x8, (u32x4){d0, d1, d2, d3});
        bop[1][qh] = __builtin_bit_cast(f16x8, (u32x4){d4, d5, d6, d7});
      }

      // ---- PV: O^T += V^T . P^T, K-steps ks16 over this skhalf ----
#pragma unroll
      for (int ks16 = 0; ks16 < 2; ++ks16) {
#pragma unroll
        for (int dhh = 0; dhh < 2; ++dhh) {
          const int vrow = dhh * 32 + l31;
          f16x8 va = *(const f16x8*)(&Vs[buf][vrow * 64 + (((skh * 4 + ks16 * 2 + hi) ^ (vrow & 7)) * 8)]);
          o[dhh][0] = __builtin_amdgcn_mfma_f32_32x32x16_f16(va, bop[ks16][0], o[dhh][0], 0, 0, 0);
          o[dhh][1] = __builtin_amdgcn_mfma_f32_32x32x16_f16(va, bop[ks16][1], o[dhh][1], 0, 0, 0);
        }
      }
    }
  }

  // epilogue: cross-half l reduce (partner shares same q col), normalize, store
#pragma unroll
  for (int qh = 0; qh < 2; ++qh) {
    float l = lsum[qh];
    l += __shfl_xor(l, 32, 64);
    float inv = 1.f / l;
    int sq = s0 + w * 64 + qh * 32 + l31;
    float* obase = out + ((size_t)b * SEQ + sq) * D_MODEL + h * DH;
#pragma unroll
    for (int dhh = 0; dhh < 2; ++dhh)
#pragma unroll
      for (int g = 0; g < 4; ++g) {
        f32x4 vv;
#pragma unroll
        for (int r = 0; r < 4; ++r) vv[r] = o[dhh][qh][g * 4 + r] * inv;
        *(f32x4*)(obase + dhh * 32 + g * 8 + hi * 4) = vv;
      }
  }
}

extern "C" void kernel_launch(void* const* d_in, const int* in_sizes, int n_in,
                              void* d_out, int out_size, void* d_ws, size_t ws_size,
                              hipStream_t stream) {
  const float* x  = (const float*)d_in[0];
  const float* Wq = (const float*)d_in[1];
  const float* bq = (const float*)d_in[2];
  const float* Wk = (const float*)d_in[3];
  const float* bk = (const float*)d_in[4];
  const float* Wv = (const float*)d_in[5];
  const float* bv = (const float*)d_in[6];
  float* out = (float*)d_out;

  char* ws = (char*)d_ws;
  f16* xb = (f16*)ws;
  f16* wt = (f16*)(ws + (size_t)16 * 1024 * 1024);
  f16* q  = (f16*)(ws + (size_t)22 * 1024 * 1024);
  f16* kk = q + (size_t)BATCH * SEQ * D_MODEL;
  f16* vt = kk + (size_t)BATCH * SEQ * D_MODEL;

  prep_kernel<<<8192 + 768, 256, 0, stream>>>(x, Wq, Wk, Wv, xb, wt);
  qkv_gemm_kernel<<<1536, 256, 0, stream>>>(xb, wt, bq, bk, bv, q, kk, vt);
  attn_kernel<<<dim3(64, 16), 128, 0, stream>>>(q, kk, vt, out);
}